// Round 9
// baseline (222.317 us; speedup 1.0000x reference)
//
#include <hip/hip_runtime.h>
#include <hip/hip_bf16.h>

// ScoreAttention on MI355X (gfx950).
// Pipeline: gn_stats_part+convert_w -> gn_apply(stats folded) -> qkv_gemm
//           -> flash_part(x4 K-split) -> merge_parts -> proj_gemm
// flash v9: 32x32x16 MFMAs, 32-key software-pipelined stages (next-stage QK MFMA
// issued between DS-write and DS-read of current stage; K/V prefetched one stage
// ahead), __launch_bounds__(256,4) to force 4 waves/SIMD, P rows 36 shorts,
// XCD-pinned grid (blockIdx.x = bh), max-free exp2 softmax, bf16 partials.

typedef __attribute__((ext_vector_type(8))) __bf16 bf16x8;
typedef __attribute__((ext_vector_type(4))) float f32x4;
typedef __attribute__((ext_vector_type(2))) float f32x2;
typedef __attribute__((ext_vector_type(16))) float f32x16;

#define HW 4096
#define C 256
#define NH 8
#define HD 32
#define QSCALE 0.25505654f  /* log2(e)/sqrt(32) */
#define PST 36              /* shorts per 32-key P row: 18 dwords, 8B-aligned, 2-way banks */

__device__ inline unsigned short f2bf(float f) {
  union { float f; unsigned int u; } v; v.f = f;
  unsigned int u = v.u;
  return (unsigned short)((u + 0x7fffu + ((u >> 16) & 1u)) >> 16);
}

__device__ inline bf16x8 load8(const unsigned short* p) {
  bf16x8 v;
  __builtin_memcpy(&v, __builtin_assume_aligned(p, 16), 16);
  return v;
}

// 8B-aligned LDS read of 8 bf16 as two b64s
__device__ inline bf16x8 load8_lds(const unsigned short* p) {
  uint2 a = *(const uint2*)__builtin_assume_aligned(p, 8);
  uint2 b = *(const uint2*)__builtin_assume_aligned(p + 4, 8);
  union { uint4 u; bf16x8 v; } cv;
  cv.u = make_uint4(a.x, a.y, b.x, b.y);
  return cv.v;
}

__device__ inline unsigned int fbits(float f) {
  unsigned int u; __builtin_memcpy(&u, &f, 4); return u;
}
__device__ inline float bits2f(unsigned int u) {
  float f; __builtin_memcpy(&f, &u, 4); return f;
}

// pack two f32 -> two bf16 in one dword (round via +0x8000)
__device__ inline unsigned int pack_bf2(float lo, float hi) {
  return __builtin_amdgcn_perm(fbits(hi) + 0x8000u, fbits(lo) + 0x8000u, 0x07060302u);
}
// truncating pack (1 instr) — for P, where the error budget is generous
__device__ inline unsigned int pack_bf2t(float lo, float hi) {
  return __builtin_amdgcn_perm(fbits(hi), fbits(lo), 0x07060302u);
}

// ---------------- GroupNorm partial stats (blocks 0..255) + weight conv (256..511)
__global__ __launch_bounds__(256) void gn_stats_part(const float* __restrict__ x,
                                                     float* __restrict__ parts,
                                                     const float* __restrict__ wq,
                                                     const float* __restrict__ wp,
                                                     unsigned short* __restrict__ wq_b,
                                                     unsigned short* __restrict__ wp_b) {
  if (blockIdx.x >= 256) {
    int base = (blockIdx.x - 256) * 1024 + threadIdx.x * 4;
    #pragma unroll
    for (int k = 0; k < 4; k++) {
      int idx = base + k;
      if (idx < 196608) wq_b[idx] = f2bf(wq[idx]);
      else              wp_b[idx - 196608] = f2bf(wp[idx - 196608]);
    }
    return;
  }
  int i = blockIdx.x;
  const float4* p4 = (const float4*)(x + (size_t)i * 8192);
  int t = threadIdx.x;
  float s = 0.f, ss = 0.f;
  for (int k = t; k < 2048; k += 256) {
    float4 v = p4[k];
    s  += v.x + v.y + v.z + v.w;
    ss += v.x*v.x + v.y*v.y + v.z*v.z + v.w*v.w;
  }
  for (int m = 32; m >= 1; m >>= 1) {
    s  += __shfl_down(s, m, 64);
    ss += __shfl_down(ss, m, 64);
  }
  __shared__ float red[8];
  int w = t >> 6;
  if ((t & 63) == 0) { red[w] = s; red[w + 4] = ss; }
  __syncthreads();
  if (t == 0) {
    parts[i]       = red[0] + red[1] + red[2] + red[3];
    parts[256 + i] = red[4] + red[5] + red[6] + red[7];
  }
}

// ---------------- GroupNorm apply + transpose (finalizes stats from parts)
__global__ __launch_bounds__(256) void gn_apply(const float* __restrict__ x,
                                                const float* __restrict__ parts,
                                                const float* __restrict__ gamma,
                                                const float* __restrict__ beta,
                                                unsigned short* __restrict__ h_t) {
  __shared__ float tile[64][65];
  __shared__ float gmean[8], grstd[8];
  int b = blockIdx.z, c0 = blockIdx.y * 64, s0 = blockIdx.x * 64;
  int t = threadIdx.x;
  if (t < 8) {
    int bg = b * 32 + (c0 >> 3) + t;
    float s  = (parts[4*bg] + parts[4*bg+1]) + (parts[4*bg+2] + parts[4*bg+3]);
    float ss = (parts[256+4*bg] + parts[256+4*bg+1]) + (parts[256+4*bg+2] + parts[256+4*bg+3]);
    float mean = s * (1.0f / 32768.0f);
    float var  = ss * (1.0f / 32768.0f) - mean * mean;
    gmean[t] = mean;
    grstd[t] = rsqrtf(var + 1e-5f);
  }
  const float* xb = x + ((size_t)b * C + c0) * HW + s0;
  #pragma unroll
  for (int k = 0; k < 16; k++) {
    int e = k * 256 + t;
    int i = e >> 6, j = e & 63;
    tile[i][j] = xb[(size_t)i * HW + j];
  }
  __syncthreads();
  unsigned short* hb = h_t + ((size_t)b * HW + s0) * C + c0;
  #pragma unroll
  for (int k = 0; k < 16; k++) {
    int e = k * 256 + t;
    int jr = e >> 6, ir = e & 63;
    int c = c0 + ir, gl = ir >> 3;
    float v = (tile[ir][jr] - gmean[gl]) * grstd[gl] * gamma[c] + beta[c];
    hb[(size_t)jr * C + ir] = f2bf(v);
  }
}

// ---------------- QKV GEMM: packed uint2 epilogue stores for q/k
__global__ __launch_bounds__(256) void qkv_gemm(const unsigned short* __restrict__ wq_b,
                                                const unsigned short* __restrict__ h_t,
                                                const float* __restrict__ b_qkv,
                                                unsigned short* __restrict__ q_t,
                                                unsigned short* __restrict__ k_t,
                                                unsigned short* __restrict__ v_t) {
  int lane = threadIdx.x & 63, w = threadIdx.x >> 6;
  int quad = lane >> 4, l16 = lane & 15;
  int m0 = blockIdx.y * 64 + w * 16;
  int n0 = blockIdx.x * 64;
  int b  = blockIdx.z;
  f32x4 acc[4];
  #pragma unroll
  for (int nb = 0; nb < 4; nb++) acc[nb] = (f32x4){0.f, 0.f, 0.f, 0.f};

  const unsigned short* hb = h_t + (size_t)b * HW * C;
  for (int k0 = 0; k0 < 256; k0 += 32) {
    bf16x8 a = load8(wq_b + (size_t)(m0 + l16) * 256 + k0 + quad * 8);
    #pragma unroll
    for (int nb = 0; nb < 4; nb++) {
      int s = n0 + nb * 16 + l16;
      bf16x8 bb = load8(hb + (size_t)s * C + k0 + quad * 8);
      acc[nb] = __builtin_amdgcn_mfma_f32_16x16x32_bf16(a, bb, acc[nb], 0, 0, 0);
    }
  }

  int seg = m0 >> 8;
  int o0 = m0 + quad * 4;
  #pragma unroll
  for (int nb = 0; nb < 4; nb++) {
    int s = n0 + nb * 16 + l16;
    if (seg == 2) {
      #pragma unroll
      for (int r = 0; r < 4; r++)
        v_t[((size_t)b * C + ((o0 + r) - 512)) * HW + s] = f2bf(acc[nb][r] + b_qkv[o0 + r]);
    } else {
      float sc = seg ? 1.0f : QSCALE;
      float v0 = (acc[nb][0] + b_qkv[o0])     * sc;
      float v1 = (acc[nb][1] + b_qkv[o0 + 1]) * sc;
      float v2 = (acc[nb][2] + b_qkv[o0 + 2]) * sc;
      float v3 = (acc[nb][3] + b_qkv[o0 + 3]) * sc;
      int oc = o0 & 255, h = oc >> 5, d = oc & 31;
      unsigned short* dst = seg ? k_t : q_t;
      uint2 dd;
      dd.x = pack_bf2(v0, v1);
      dd.y = pack_bf2(v2, v3);
      *(uint2*)(dst + (((size_t)b * NH + h) * HW + s) * HD + d) = dd;
    }
  }
}

// ---- flash v9 helpers (one 32-key stage) ----
struct KF { bf16x8 lo, hi; };

__device__ __forceinline__ KF loadK(const unsigned short* K, int j, int n, int hi8) {
  const unsigned short* kp = K + (size_t)(j + n) * HD + hi8;
  KF r; r.lo = load8(kp); r.hi = load8(kp + 16);
  return r;
}
__device__ __forceinline__ void loadV(const unsigned short* V, int j, int hi8, bf16x8* vf) {
  vf[0] = load8(V + j + hi8);
  vf[1] = load8(V + j + 16 + hi8);
}
// softmax on S (one 32-key block) + pack to LDS row; returns updated psum
__device__ __forceinline__ void softmax_pack(const f32x16& S, unsigned short* prow,
                                             int hi, f32x2& ps2) {
  float p[16];
  #pragma unroll
  for (int r = 0; r < 16; r++)
    p[r] = __builtin_amdgcn_exp2f(S[r]);
  f32x2 t0 = (f32x2){p[0], p[1]} + (f32x2){p[2], p[3]};
  f32x2 t1 = (f32x2){p[4], p[5]} + (f32x2){p[6], p[7]};
  f32x2 t2 = (f32x2){p[8], p[9]} + (f32x2){p[10], p[11]};
  f32x2 t3 = (f32x2){p[12], p[13]} + (f32x2){p[14], p[15]};
  ps2 += (t0 + t1) + (t2 + t3);
  #pragma unroll
  for (int g = 0; g < 4; g++) {
    uint2 dd;
    dd.x = pack_bf2t(p[4 * g], p[4 * g + 1]);
    dd.y = pack_bf2t(p[4 * g + 2], p[4 * g + 3]);
    // P[key g*8 + 4*hi + {0..3}] within this 32-key row
    *(uint2*)(prow + g * 8 + hi * 4) = dd;
  }
}

// ---------------- Flash v9: grid (bh=16, qtile=32, split=4), 4 waves/block
__global__ __launch_bounds__(256, 4) void flash_part(const unsigned short* __restrict__ q_t,
                                                     const unsigned short* __restrict__ k_t,
                                                     const unsigned short* __restrict__ v_t,
                                                     unsigned short* __restrict__ po,
                                                     float* __restrict__ pl,
                                                     int jspan) {
  int lane = threadIdx.x & 63, w = threadIdx.x >> 6;
  int n = lane & 31, hi = lane >> 5;
  int hi8 = hi * 8;
  int bh = blockIdx.x, b = bh >> 3, h = bh & 7;
  int m0 = blockIdx.y * 128 + w * 32;
  int z = blockIdx.z;

  __shared__ __align__(16) unsigned short pbuf[4][32 * PST];
  unsigned short* prow = &pbuf[w][0] + n * PST;

  const unsigned short* Q = q_t + (size_t)bh * HW * HD;
  const unsigned short* K = k_t + (size_t)bh * HW * HD;
  const unsigned short* V = v_t + ((size_t)b * C + h * HD) * HW + (size_t)n * HW;

  // B-operand Q fragments: lane holds query n, k = dhalf*16 + hi*8 + j
  bf16x8 qf0 = load8(Q + (size_t)(m0 + n) * HD + hi8);
  bf16x8 qf1 = load8(Q + (size_t)(m0 + n) * HD + 16 + hi8);

  f32x2 ps2 = (f32x2){0.f, 0.f};
  f32x16 oT = (f32x16){0.f,0.f,0.f,0.f,0.f,0.f,0.f,0.f,0.f,0.f,0.f,0.f,0.f,0.f,0.f,0.f};
  const f32x16 zero16 = (f32x16){0.f,0.f,0.f,0.f,0.f,0.f,0.f,0.f,0.f,0.f,0.f,0.f,0.f,0.f,0.f,0.f};

  int jbase = z * jspan;
  int jend  = jbase + jspan;

  // ---- pipeline preamble: stage A = keys [jbase, jbase+32), B = [jbase+32, ...)
  KF kfA = loadK(K, jbase, n, hi8);
  bf16x8 vfA[2]; loadV(V, jbase, hi8, vfA);
  f32x16 SA = __builtin_amdgcn_mfma_f32_32x32x16_bf16(kfA.hi, qf1, zero16, 0, 0, 0);
  SA = __builtin_amdgcn_mfma_f32_32x32x16_bf16(kfA.lo, qf0, SA, 0, 0, 0);
  KF kfB = loadK(K, jbase + 32, n, hi8);
  bf16x8 vfB[2]; loadV(V, jbase + 32, hi8, vfB);

  for (int j0 = jbase; j0 < jend; j0 += 64) {
    int jA2 = (j0 + 64 < jend) ? j0 + 64 : jbase;
    int jB2 = (j0 + 96 < jend) ? j0 + 96 : jbase;
    // ======== stage A ========
    softmax_pack(SA, prow, hi, ps2);                       // exp/pack/ds_write A
    f32x16 SB = __builtin_amdgcn_mfma_f32_32x32x16_bf16(kfB.hi, qf1, zero16, 0, 0, 0);
    SB = __builtin_amdgcn_mfma_f32_32x32x16_bf16(kfB.lo, qf0, SB, 0, 0, 0);
    KF kfA2 = loadK(K, jA2, n, hi8);                       // prefetch next-A
    bf16x8 vfA2[2]; loadV(V, jA2, hi8, vfA2);
    {  // PV A (reads P written above; QK-B MFMAs + prefetch cover DS latency)
      bf16x8 pf0 = load8_lds(prow + hi8);
      bf16x8 pf1 = load8_lds(prow + 16 + hi8);
      oT = __builtin_amdgcn_mfma_f32_32x32x16_bf16(vfA[0], pf0, oT, 0, 0, 0);
      oT = __builtin_amdgcn_mfma_f32_32x32x16_bf16(vfA[1], pf1, oT, 0, 0, 0);
    }
    // ======== stage B ========
    softmax_pack(SB, prow, hi, ps2);                       // exp/pack/ds_write B
    SA = __builtin_amdgcn_mfma_f32_32x32x16_bf16(kfA2.hi, qf1, zero16, 0, 0, 0);
    SA = __builtin_amdgcn_mfma_f32_32x32x16_bf16(kfA2.lo, qf0, SA, 0, 0, 0);
    kfB = loadK(K, jB2, n, hi8);                           // prefetch next-B
    {
      bf16x8 pf0 = load8_lds(prow + hi8);
      bf16x8 pf1 = load8_lds(prow + 16 + hi8);
      oT = __builtin_amdgcn_mfma_f32_32x32x16_bf16(vfB[0], pf0, oT, 0, 0, 0);
      oT = __builtin_amdgcn_mfma_f32_32x32x16_bf16(vfB[1], pf1, oT, 0, 0, 0);
    }
    vfA[0] = vfA2[0]; vfA[1] = vfA2[1];
    loadV(V, jB2, hi8, vfB);
  }

  float psum = ps2.x + ps2.y;
  psum += __shfl_xor(psum, 32, 64);

  // O^T partials (bf16): col=query n, row d = (reg&3)+8*(reg>>2)+4*hi
  unsigned short* pr = po + (((size_t)z * 16 + bh) * HW + (m0 + n)) * 32;
  #pragma unroll
  for (int g = 0; g < 4; g++) {
    uint2 dd;
    dd.x = pack_bf2(oT[4 * g], oT[4 * g + 1]);
    dd.y = pack_bf2(oT[4 * g + 2], oT[4 * g + 3]);
    *(uint2*)(pr + g * 8 + hi * 4) = dd;
  }
  if (lane < 32)
    pl[((size_t)z * 16 + bh) * HW + m0 + n] = psum;
}

// ---------------- merge 4 partials -> ao_t[b][s][c] bf16
__global__ __launch_bounds__(256) void merge_parts(const unsigned short* __restrict__ po,
                                                   const float* __restrict__ pl,
                                                   unsigned short* __restrict__ ao_t) {
  int g = blockIdx.x * 256 + threadIdx.x;   // [0, 16*4096*4)
  int q4 = g & 3, s = (g >> 2) & 4095, bh = g >> 14;
  const uint4* p4 = (const uint4*)po;
  size_t idx = ((size_t)bh * HW + s) * 4 + q4;
  const size_t zstride = (size_t)16 * HW * 4;
  float acc[8] = {0,0,0,0,0,0,0,0};
  float l = 0.f;
  #pragma unroll
  for (int z = 0; z < 4; z++) {
    uint4 v = p4[z * zstride + idx];
    acc[0] += bits2f(v.x << 16);  acc[1] += bits2f(v.x & 0xffff0000u);
    acc[2] += bits2f(v.y << 16);  acc[3] += bits2f(v.y & 0xffff0000u);
    acc[4] += bits2f(v.z << 16);  acc[5] += bits2f(v.z & 0xffff0000u);
    acc[6] += bits2f(v.w << 16);  acc[7] += bits2f(v.w & 0xffff0000u);
    l += pl[((size_t)z * 16 + bh) * HW + s];
  }
  float inv = 1.0f / l;
  int b = bh >> 3, h = bh & 7;
  uint4 o;
  o.x = pack_bf2(acc[0] * inv, acc[1] * inv);
  o.y = pack_bf2(acc[2] * inv, acc[3] * inv);
  o.z = pack_bf2(acc[4] * inv, acc[5] * inv);
  o.w = pack_bf2(acc[6] * inv, acc[7] * inv);
  *(uint4*)(ao_t + ((size_t)b * HW + s) * C + h * HD + q4 * 8) = o;
}

// ---------------- Proj GEMM + bias + residual
__global__ __launch_bounds__(256) void proj_gemm(const unsigned short* __restrict__ wp_b,
                                                 const unsigned short* __restrict__ ao_t,
                                                 const float* __restrict__ b_proj,
                                                 const float* __restrict__ x,
                                                 float* __restrict__ out) {
  int lane = threadIdx.x & 63, w = threadIdx.x >> 6;
  int quad = lane >> 4, l16 = lane & 15;
  int m0 = blockIdx.y * 64 + w * 16;
  int n0 = blockIdx.x * 64;
  int b  = blockIdx.z;
  f32x4 acc[4];
  #pragma unroll
  for (int nb = 0; nb < 4; nb++) acc[nb] = (f32x4){0.f, 0.f, 0.f, 0.f};

  const unsigned short* ab = ao_t + (size_t)b * HW * C;
  for (int k0 = 0; k0 < 256; k0 += 32) {
    bf16x8 a = load8(wp_b + (size_t)(m0 + l16) * 256 + k0 + quad * 8);
    #pragma unroll
    for (int nb = 0; nb < 4; nb++) {
      int s = n0 + nb * 16 + l16;
      bf16x8 bb = load8(ab + (size_t)s * C + k0 + quad * 8);
      acc[nb] = __builtin_amdgcn_mfma_f32_16x16x32_bf16(a, bb, acc[nb], 0, 0, 0);
    }
  }
  #pragma unroll
  for (int nb = 0; nb < 4; nb++) {
    int s = n0 + nb * 16 + l16;
    #pragma unroll
    for (int r = 0; r < 4; r++) {
      int o = m0 + quad * 4 + r;
      size_t idx = ((size_t)b * C + o) * HW + s;
      out[idx] = acc[nb][r] + b_proj[o] + x[idx];
    }
  }
}

extern "C" void kernel_launch(void* const* d_in, const int* in_sizes, int n_in,
                              void* d_out, int out_size, void* d_ws, size_t ws_size,
                              hipStream_t stream) {
  const float* x      = (const float*)d_in[0];
  const float* w_qkv  = (const float*)d_in[1];
  const float* b_qkv  = (const float*)d_in[2];
  const float* w_proj = (const float*)d_in[3];
  const float* b_proj = (const float*)d_in[4];
  const float* gamma  = (const float*)d_in[5];
  const float* beta   = (const float*)d_in[6];
  float* out = (float*)d_out;

  char* ws = (char*)d_ws;
  float*          parts = (float*)ws;                          // 2 KB
  unsigned short* wq_b  = (unsigned short*)(ws + 4096);        // 384 KB
  unsigned short* wp_b  = (unsigned short*)(ws + 397312);      // 128 KB
  unsigned short* h_t   = (unsigned short*)(ws + 528384);      // 4 MB [b][s][c]; reused as ao_t
  unsigned short* q_t   = (unsigned short*)(ws + 4722688);     // 4 MB [bh][s][d]
  unsigned short* k_t   = (unsigned short*)(ws + 8916992);     // 4 MB [bh][s][d]
  unsigned short* v_t   = (unsigned short*)(ws + 13111296);    // 4 MB [b][c][s]
  unsigned short* po    = (unsigned short*)(ws + 17305600);    // 16 MB (4 splits, bf16)
  float*          pl    = (float*)(ws + 34082816);             // 1 MB
  unsigned short* ao_t  = h_t;  // h_t dead after qkv_gemm

  gn_stats_part<<<512, 256, 0, stream>>>(x, parts, w_qkv, w_proj, wq_b, wp_b);
  gn_apply<<<dim3(64, 4, 2), 256, 0, stream>>>(x, parts, gamma, beta, h_t);
  qkv_gemm<<<dim3(64, 12, 2), 256, 0, stream>>>(wq_b, h_t, b_qkv, q_t, k_t, v_t);
  flash_part<<<dim3(16, 32, 4), 256, 0, stream>>>(q_t, k_t, v_t, po, pl, HW / 4);
  merge_parts<<<1024, 256, 0, stream>>>(po, pl, ao_t);
  proj_gemm<<<dim3(64, 4, 2), 256, 0, stream>>>(wp_b, ao_t, b_proj, x, out);
}

// Round 10
// 185.823 us; speedup vs baseline: 1.1964x; 1.1964x over previous
//
#include <hip/hip_runtime.h>
#include <hip/hip_bf16.h>

// ScoreAttention on MI355X (gfx950).
// Pipeline: gn_stats_part+convert_w -> gn_apply(stats folded) -> qkv_gemm
//           -> flash_part(x4 K-split) -> merge_parts -> proj_gemm
// flash v10: block-cooperative COALESCED K/V staging into LDS (each thread one
// contiguous 16B load, reg-prefetched one iter ahead) -- kills the strided-gather
// TA/L1 bottleneck that pinned v4-v9 at ~105us. 32x32x16 MFMAs, max-free exp2
// softmax, P via per-wave LDS rows, XCD-pinned grid (blockIdx.x = bh).

typedef __attribute__((ext_vector_type(8))) __bf16 bf16x8;
typedef __attribute__((ext_vector_type(4))) float f32x4;
typedef __attribute__((ext_vector_type(2))) float f32x2;
typedef __attribute__((ext_vector_type(16))) float f32x16;

#define HW 4096
#define C 256
#define NH 8
#define HD 32
#define QSCALE 0.25505654f  /* log2(e)/sqrt(32) */
#define KST 36   /* K tile row stride (shorts): [key][32d + pad] */
#define VST 68   /* V tile row stride (shorts): [d][64keys + pad] */
#define PST 36   /* P row stride (shorts): [query][32keys + pad] */

__device__ inline unsigned short f2bf(float f) {
  union { float f; unsigned int u; } v; v.f = f;
  unsigned int u = v.u;
  return (unsigned short)((u + 0x7fffu + ((u >> 16) & 1u)) >> 16);
}

__device__ inline bf16x8 load8(const unsigned short* p) {
  bf16x8 v;
  __builtin_memcpy(&v, __builtin_assume_aligned(p, 16), 16);
  return v;
}

// 8B-aligned LDS read of 8 bf16 as two b64s
__device__ inline bf16x8 load8_lds(const unsigned short* p) {
  uint2 a = *(const uint2*)__builtin_assume_aligned(p, 8);
  uint2 b = *(const uint2*)__builtin_assume_aligned(p + 4, 8);
  union { uint4 u; bf16x8 v; } cv;
  cv.u = make_uint4(a.x, a.y, b.x, b.y);
  return cv.v;
}

__device__ inline unsigned int fbits(float f) {
  unsigned int u; __builtin_memcpy(&u, &f, 4); return u;
}
__device__ inline float bits2f(unsigned int u) {
  float f; __builtin_memcpy(&f, &u, 4); return f;
}

// pack two f32 -> two bf16 in one dword (round via +0x8000)
__device__ inline unsigned int pack_bf2(float lo, float hi) {
  return __builtin_amdgcn_perm(fbits(hi) + 0x8000u, fbits(lo) + 0x8000u, 0x07060302u);
}
// truncating pack (1 instr) — for P, where the error budget is generous
__device__ inline unsigned int pack_bf2t(float lo, float hi) {
  return __builtin_amdgcn_perm(fbits(hi), fbits(lo), 0x07060302u);
}

// ---------------- GroupNorm partial stats (blocks 0..255) + weight conv (256..511)
__global__ __launch_bounds__(256) void gn_stats_part(const float* __restrict__ x,
                                                     float* __restrict__ parts,
                                                     const float* __restrict__ wq,
                                                     const float* __restrict__ wp,
                                                     unsigned short* __restrict__ wq_b,
                                                     unsigned short* __restrict__ wp_b) {
  if (blockIdx.x >= 256) {
    int base = (blockIdx.x - 256) * 1024 + threadIdx.x * 4;
    #pragma unroll
    for (int k = 0; k < 4; k++) {
      int idx = base + k;
      if (idx < 196608) wq_b[idx] = f2bf(wq[idx]);
      else              wp_b[idx - 196608] = f2bf(wp[idx - 196608]);
    }
    return;
  }
  int i = blockIdx.x;
  const float4* p4 = (const float4*)(x + (size_t)i * 8192);
  int t = threadIdx.x;
  float s = 0.f, ss = 0.f;
  for (int k = t; k < 2048; k += 256) {
    float4 v = p4[k];
    s  += v.x + v.y + v.z + v.w;
    ss += v.x*v.x + v.y*v.y + v.z*v.z + v.w*v.w;
  }
  for (int m = 32; m >= 1; m >>= 1) {
    s  += __shfl_down(s, m, 64);
    ss += __shfl_down(ss, m, 64);
  }
  __shared__ float red[8];
  int w = t >> 6;
  if ((t & 63) == 0) { red[w] = s; red[w + 4] = ss; }
  __syncthreads();
  if (t == 0) {
    parts[i]       = red[0] + red[1] + red[2] + red[3];
    parts[256 + i] = red[4] + red[5] + red[6] + red[7];
  }
}

// ---------------- GroupNorm apply + transpose (finalizes stats from parts)
__global__ __launch_bounds__(256) void gn_apply(const float* __restrict__ x,
                                                const float* __restrict__ parts,
                                                const float* __restrict__ gamma,
                                                const float* __restrict__ beta,
                                                unsigned short* __restrict__ h_t) {
  __shared__ float tile[64][65];
  __shared__ float gmean[8], grstd[8];
  int b = blockIdx.z, c0 = blockIdx.y * 64, s0 = blockIdx.x * 64;
  int t = threadIdx.x;
  if (t < 8) {
    int bg = b * 32 + (c0 >> 3) + t;
    float s  = (parts[4*bg] + parts[4*bg+1]) + (parts[4*bg+2] + parts[4*bg+3]);
    float ss = (parts[256+4*bg] + parts[256+4*bg+1]) + (parts[256+4*bg+2] + parts[256+4*bg+3]);
    float mean = s * (1.0f / 32768.0f);
    float var  = ss * (1.0f / 32768.0f) - mean * mean;
    gmean[t] = mean;
    grstd[t] = rsqrtf(var + 1e-5f);
  }
  const float* xb = x + ((size_t)b * C + c0) * HW + s0;
  #pragma unroll
  for (int k = 0; k < 16; k++) {
    int e = k * 256 + t;
    int i = e >> 6, j = e & 63;
    tile[i][j] = xb[(size_t)i * HW + j];
  }
  __syncthreads();
  unsigned short* hb = h_t + ((size_t)b * HW + s0) * C + c0;
  #pragma unroll
  for (int k = 0; k < 16; k++) {
    int e = k * 256 + t;
    int jr = e >> 6, ir = e & 63;
    int c = c0 + ir, gl = ir >> 3;
    float v = (tile[ir][jr] - gmean[gl]) * grstd[gl] * gamma[c] + beta[c];
    hb[(size_t)jr * C + ir] = f2bf(v);
  }
}

// ---------------- QKV GEMM: packed uint2 epilogue stores for q/k
__global__ __launch_bounds__(256) void qkv_gemm(const unsigned short* __restrict__ wq_b,
                                                const unsigned short* __restrict__ h_t,
                                                const float* __restrict__ b_qkv,
                                                unsigned short* __restrict__ q_t,
                                                unsigned short* __restrict__ k_t,
                                                unsigned short* __restrict__ v_t) {
  int lane = threadIdx.x & 63, w = threadIdx.x >> 6;
  int quad = lane >> 4, l16 = lane & 15;
  int m0 = blockIdx.y * 64 + w * 16;
  int n0 = blockIdx.x * 64;
  int b  = blockIdx.z;
  f32x4 acc[4];
  #pragma unroll
  for (int nb = 0; nb < 4; nb++) acc[nb] = (f32x4){0.f, 0.f, 0.f, 0.f};

  const unsigned short* hb = h_t + (size_t)b * HW * C;
  for (int k0 = 0; k0 < 256; k0 += 32) {
    bf16x8 a = load8(wq_b + (size_t)(m0 + l16) * 256 + k0 + quad * 8);
    #pragma unroll
    for (int nb = 0; nb < 4; nb++) {
      int s = n0 + nb * 16 + l16;
      bf16x8 bb = load8(hb + (size_t)s * C + k0 + quad * 8);
      acc[nb] = __builtin_amdgcn_mfma_f32_16x16x32_bf16(a, bb, acc[nb], 0, 0, 0);
    }
  }

  int seg = m0 >> 8;
  int o0 = m0 + quad * 4;
  #pragma unroll
  for (int nb = 0; nb < 4; nb++) {
    int s = n0 + nb * 16 + l16;
    if (seg == 2) {
      #pragma unroll
      for (int r = 0; r < 4; r++)
        v_t[((size_t)b * C + ((o0 + r) - 512)) * HW + s] = f2bf(acc[nb][r] + b_qkv[o0 + r]);
    } else {
      float sc = seg ? 1.0f : QSCALE;
      float v0 = (acc[nb][0] + b_qkv[o0])     * sc;
      float v1 = (acc[nb][1] + b_qkv[o0 + 1]) * sc;
      float v2 = (acc[nb][2] + b_qkv[o0 + 2]) * sc;
      float v3 = (acc[nb][3] + b_qkv[o0 + 3]) * sc;
      int oc = o0 & 255, h = oc >> 5, d = oc & 31;
      unsigned short* dst = seg ? k_t : q_t;
      uint2 dd;
      dd.x = pack_bf2(v0, v1);
      dd.y = pack_bf2(v2, v3);
      *(uint2*)(dst + (((size_t)b * NH + h) * HW + s) * HD + d) = dd;
    }
  }
}

// softmax on S (one 32-key block) + pack to LDS row
__device__ __forceinline__ void softmax_pack(const f32x16& S, unsigned short* prow,
                                             int hi, f32x2& ps2) {
  float p[16];
  #pragma unroll
  for (int r = 0; r < 16; r++)
    p[r] = __builtin_amdgcn_exp2f(S[r]);
  f32x2 t0 = (f32x2){p[0], p[1]} + (f32x2){p[2], p[3]};
  f32x2 t1 = (f32x2){p[4], p[5]} + (f32x2){p[6], p[7]};
  f32x2 t2 = (f32x2){p[8], p[9]} + (f32x2){p[10], p[11]};
  f32x2 t3 = (f32x2){p[12], p[13]} + (f32x2){p[14], p[15]};
  ps2 += (t0 + t1) + (t2 + t3);
  #pragma unroll
  for (int g = 0; g < 4; g++) {
    uint2 dd;
    dd.x = pack_bf2t(p[4 * g], p[4 * g + 1]);
    dd.y = pack_bf2t(p[4 * g + 2], p[4 * g + 3]);
    // P[key g*8 + 4*hi + {0..3}] within this 32-key row
    *(uint2*)(prow + g * 8 + hi * 4) = dd;
  }
}

// ---------------- Flash v10: grid (bh=16, qtile=32, split=4), 4 waves/block
__global__ __launch_bounds__(256) void flash_part(const unsigned short* __restrict__ q_t,
                                                  const unsigned short* __restrict__ k_t,
                                                  const unsigned short* __restrict__ v_t,
                                                  unsigned short* __restrict__ po,
                                                  float* __restrict__ pl,
                                                  int jspan) {
  int t = threadIdx.x;
  int lane = t & 63, w = t >> 6;
  int n = lane & 31, hi = lane >> 5, hi8 = hi * 8;
  int bh = blockIdx.x, b = bh >> 3, h = bh & 7;
  int m0 = blockIdx.y * 128 + w * 32;
  int z = blockIdx.z;

  __shared__ __align__(16) unsigned short kt[64 * KST];        // 4.6 KB [key][d]
  __shared__ __align__(16) unsigned short vt[32 * VST];        // 4.4 KB [d][key]
  __shared__ __align__(16) unsigned short pbuf[4][32 * PST];   // 9.2 KB
  unsigned short* prow = &pbuf[w][0] + n * PST;

  const unsigned short* Q  = q_t + (size_t)bh * HW * HD;
  const unsigned short* Kg = k_t + (size_t)bh * HW * HD;
  const unsigned short* Vg = v_t + ((size_t)b * C + h * HD) * HW;

  // B-operand Q fragments: lane holds query n, k = dhalf*16 + hi*8 + j
  bf16x8 qf0 = load8(Q + (size_t)(m0 + n) * HD + hi8);
  bf16x8 qf1 = load8(Q + (size_t)(m0 + n) * HD + 16 + hi8);

  // coalesced staging roles: K tile 64keys x 32d (4KB): thread = (key, 16B seg)
  //                          V tile 32d x 64keys (4KB): thread = (d, 16B seg)
  int kkey = t >> 2, kseg = (t & 3) * 8;
  int vd   = t >> 3, vseg = (t & 7) * 8;
  const unsigned short* kgp = Kg + (size_t)kkey * HD + kseg;
  const unsigned short* vgp = Vg + (size_t)vd * HW + vseg;
  unsigned short* kwp = kt + kkey * KST + kseg;
  unsigned short* vwp = vt + vd * VST + vseg;

  f32x2 ps2 = (f32x2){0.f, 0.f};
  f32x16 oT = (f32x16){0.f,0.f,0.f,0.f,0.f,0.f,0.f,0.f,0.f,0.f,0.f,0.f,0.f,0.f,0.f,0.f};
  const f32x16 zero16 = (f32x16){0.f,0.f,0.f,0.f,0.f,0.f,0.f,0.f,0.f,0.f,0.f,0.f,0.f,0.f,0.f,0.f};

  int jbase = z * jspan, jend = jbase + jspan;
  uint4 kreg = *(const uint4*)(kgp + (size_t)jbase * HD);
  uint4 vreg = *(const uint4*)(vgp + jbase);

  for (int j0 = jbase; j0 < jend; j0 += 64) {
    __syncthreads();   // previous iteration's LDS reads complete
    *(uint2*)(kwp)     = make_uint2(kreg.x, kreg.y);
    *(uint2*)(kwp + 4) = make_uint2(kreg.z, kreg.w);
    *(uint2*)(vwp)     = make_uint2(vreg.x, vreg.y);
    *(uint2*)(vwp + 4) = make_uint2(vreg.z, vreg.w);
    // prefetch next tile (redundant re-read of jbase on last iter; harmless)
    int jn = (j0 + 64 < jend) ? (j0 + 64) : jbase;
    kreg = *(const uint4*)(kgp + (size_t)jn * HD);
    vreg = *(const uint4*)(vgp + jn);
    __syncthreads();   // staged tile visible
    #pragma unroll
    for (int kb = 0; kb < 2; kb++) {
      // QK^T: A = K[key][d] from LDS; lane (n,hi): row kb*32+n, k = dhalf*16+hi*8+j
      const unsigned short* krow = kt + (kb * 32 + n) * KST;
      bf16x8 k0 = load8_lds(krow + hi8);
      bf16x8 k1 = load8_lds(krow + 16 + hi8);
      f32x16 S = __builtin_amdgcn_mfma_f32_32x32x16_bf16(k1, qf1, zero16, 0, 0, 0);
      S = __builtin_amdgcn_mfma_f32_32x32x16_bf16(k0, qf0, S, 0, 0, 0);
      // exp2 + psum + pack P row (32 keys)
      softmax_pack(S, prow, hi, ps2);
      // PV: A = V^T[d][key] from LDS; two k=16 MFMAs cover the 32 keys
      const unsigned short* vrow = vt + n * VST + kb * 32;
      bf16x8 vf0 = load8_lds(vrow + hi8);
      bf16x8 vf1 = load8_lds(vrow + 16 + hi8);
      bf16x8 pf0 = load8_lds(prow + hi8);
      bf16x8 pf1 = load8_lds(prow + 16 + hi8);
      oT = __builtin_amdgcn_mfma_f32_32x32x16_bf16(vf0, pf0, oT, 0, 0, 0);
      oT = __builtin_amdgcn_mfma_f32_32x32x16_bf16(vf1, pf1, oT, 0, 0, 0);
    }
  }

  float psum = ps2.x + ps2.y;
  psum += __shfl_xor(psum, 32, 64);

  // O^T partials (bf16): col=query n, row d = (reg&3)+8*(reg>>2)+4*hi
  unsigned short* pr = po + (((size_t)z * 16 + bh) * HW + (m0 + n)) * 32;
  #pragma unroll
  for (int g = 0; g < 4; g++) {
    uint2 dd;
    dd.x = pack_bf2(oT[4 * g], oT[4 * g + 1]);
    dd.y = pack_bf2(oT[4 * g + 2], oT[4 * g + 3]);
    *(uint2*)(pr + g * 8 + hi * 4) = dd;
  }
  if (lane < 32)
    pl[((size_t)z * 16 + bh) * HW + m0 + n] = psum;
}

// ---------------- merge 4 partials -> ao_t[b][s][c] bf16
__global__ __launch_bounds__(256) void merge_parts(const unsigned short* __restrict__ po,
                                                   const float* __restrict__ pl,
                                                   unsigned short* __restrict__ ao_t) {
  int g = blockIdx.x * 256 + threadIdx.x;   // [0, 16*4096*4)
  int q4 = g & 3, s = (g >> 2) & 4095, bh = g >> 14;
  const uint4* p4 = (const uint4*)po;
  size_t idx = ((size_t)bh * HW + s) * 4 + q4;
  const size_t zstride = (size_t)16 * HW * 4;
  float acc[8] = {0,0,0,0,0,0,0,0};
  float l = 0.f;
  #pragma unroll
  for (int z = 0; z < 4; z++) {
    uint4 v = p4[z * zstride + idx];
    acc[0] += bits2f(v.x << 16);  acc[1] += bits2f(v.x & 0xffff0000u);
    acc[2] += bits2f(v.y << 16);  acc[3] += bits2f(v.y & 0xffff0000u);
    acc[4] += bits2f(v.z << 16);  acc[5] += bits2f(v.z & 0xffff0000u);
    acc[6] += bits2f(v.w << 16);  acc[7] += bits2f(v.w & 0xffff0000u);
    l += pl[((size_t)z * 16 + bh) * HW + s];
  }
  float inv = 1.0f / l;
  int b = bh >> 3, h = bh & 7;
  uint4 o;
  o.x = pack_bf2(acc[0] * inv, acc[1] * inv);
  o.y = pack_bf2(acc[2] * inv, acc[3] * inv);
  o.z = pack_bf2(acc[4] * inv, acc[5] * inv);
  o.w = pack_bf2(acc[6] * inv, acc[7] * inv);
  *(uint4*)(ao_t + ((size_t)b * HW + s) * C + h * HD + q4 * 8) = o;
}

// ---------------- Proj GEMM + bias + residual
__global__ __launch_bounds__(256) void proj_gemm(const unsigned short* __restrict__ wp_b,
                                                 const unsigned short* __restrict__ ao_t,
                                                 const float* __restrict__ b_proj,
                                                 const float* __restrict__ x,
                                                 float* __restrict__ out) {
  int lane = threadIdx.x & 63, w = threadIdx.x >> 6;
  int quad = lane >> 4, l16 = lane & 15;
  int m0 = blockIdx.y * 64 + w * 16;
  int n0 = blockIdx.x * 64;
  int b  = blockIdx.z;
  f32x4 acc[4];
  #pragma unroll
  for (int nb = 0; nb < 4; nb++) acc[nb] = (f32x4){0.f, 0.f, 0.f, 0.f};

  const unsigned short* ab = ao_t + (size_t)b * HW * C;
  for (int k0 = 0; k0 < 256; k0 += 32) {
    bf16x8 a = load8(wp_b + (size_t)(m0 + l16) * 256 + k0 + quad * 8);
    #pragma unroll
    for (int nb = 0; nb < 4; nb++) {
      int s = n0 + nb * 16 + l16;
      bf16x8 bb = load8(ab + (size_t)s * C + k0 + quad * 8);
      acc[nb] = __builtin_amdgcn_mfma_f32_16x16x32_bf16(a, bb, acc[nb], 0, 0, 0);
    }
  }
  #pragma unroll
  for (int nb = 0; nb < 4; nb++) {
    int s = n0 + nb * 16 + l16;
    #pragma unroll
    for (int r = 0; r < 4; r++) {
      int o = m0 + quad * 4 + r;
      size_t idx = ((size_t)b * C + o) * HW + s;
      out[idx] = acc[nb][r] + b_proj[o] + x[idx];
    }
  }
}

extern "C" void kernel_launch(void* const* d_in, const int* in_sizes, int n_in,
                              void* d_out, int out_size, void* d_ws, size_t ws_size,
                              hipStream_t stream) {
  const float* x      = (const float*)d_in[0];
  const float* w_qkv  = (const float*)d_in[1];
  const float* b_qkv  = (const float*)d_in[2];
  const float* w_proj = (const float*)d_in[3];
  const float* b_proj = (const float*)d_in[4];
  const float* gamma  = (const float*)d_in[5];
  const float* beta   = (const float*)d_in[6];
  float* out = (float*)d_out;

  char* ws = (char*)d_ws;
  float*          parts = (float*)ws;                          // 2 KB
  unsigned short* wq_b  = (unsigned short*)(ws + 4096);        // 384 KB
  unsigned short* wp_b  = (unsigned short*)(ws + 397312);      // 128 KB
  unsigned short* h_t   = (unsigned short*)(ws + 528384);      // 4 MB [b][s][c]; reused as ao_t
  unsigned short* q_t   = (unsigned short*)(ws + 4722688);     // 4 MB [bh][s][d]
  unsigned short* k_t   = (unsigned short*)(ws + 8916992);     // 4 MB [bh][s][d]
  unsigned short* v_t   = (unsigned short*)(ws + 13111296);    // 4 MB [b][c][s]
  unsigned short* po    = (unsigned short*)(ws + 17305600);    // 16 MB (4 splits, bf16)
  float*          pl    = (float*)(ws + 34082816);             // 1 MB
  unsigned short* ao_t  = h_t;  // h_t dead after qkv_gemm

  gn_stats_part<<<512, 256, 0, stream>>>(x, parts, w_qkv, w_proj, wq_b, wp_b);
  gn_apply<<<dim3(64, 4, 2), 256, 0, stream>>>(x, parts, gamma, beta, h_t);
  qkv_gemm<<<dim3(64, 12, 2), 256, 0, stream>>>(wq_b, h_t, b_qkv, q_t, k_t, v_t);
  flash_part<<<dim3(16, 32, 4), 256, 0, stream>>>(q_t, k_t, v_t, po, pl, HW / 4);
  merge_parts<<<1024, 256, 0, stream>>>(po, pl, ao_t);
  proj_gemm<<<dim3(64, 4, 2), 256, 0, stream>>>(wp_b, ao_t, b_proj, x, out);
}

// Round 12
// 183.515 us; speedup vs baseline: 1.2114x; 1.0126x over previous
//
#include <hip/hip_runtime.h>
#include <hip/hip_bf16.h>

// ScoreAttention on MI355X (gfx950).
// Pipeline: gn_stats_part+convert_w -> gn_apply(stats folded) -> qkv_gemm
//           -> flash_part(x2 K-split) -> merge_parts -> proj_gemm
// flash v11b: coalesced double-buffered K/V LDS staging (ONE barrier per 64-key
// tile), QK->softmax->PV batched across both 32-key blocks so 64 exp2 separate
// the P LDS write from its read. 32x32x16 MFMAs, max-free exp2 softmax,
// XCD-pinned grid (blockIdx.x = bh), bf16 partials, K-split=2.
// (v11 bug fixed: K A-fragment loads were missing the +hi8 half-wave offset.)

typedef __attribute__((ext_vector_type(8))) __bf16 bf16x8;
typedef __attribute__((ext_vector_type(4))) float f32x4;
typedef __attribute__((ext_vector_type(2))) float f32x2;
typedef __attribute__((ext_vector_type(16))) float f32x16;

#define HW 4096
#define C 256
#define NH 8
#define HD 32
#define QSCALE 0.25505654f  /* log2(e)/sqrt(32) */
#define KST 36   /* K tile row stride (shorts): [key][32d + pad] */
#define VST 68   /* V tile row stride (shorts): [d][64keys + pad] */
#define PST 36   /* P row stride (shorts) per 32-key block */

__device__ inline unsigned short f2bf(float f) {
  union { float f; unsigned int u; } v; v.f = f;
  unsigned int u = v.u;
  return (unsigned short)((u + 0x7fffu + ((u >> 16) & 1u)) >> 16);
}

__device__ inline bf16x8 load8(const unsigned short* p) {
  bf16x8 v;
  __builtin_memcpy(&v, __builtin_assume_aligned(p, 16), 16);
  return v;
}

// 8B-aligned LDS read of 8 bf16 as two b64s
__device__ inline bf16x8 load8_lds(const unsigned short* p) {
  uint2 a = *(const uint2*)__builtin_assume_aligned(p, 8);
  uint2 b = *(const uint2*)__builtin_assume_aligned(p + 4, 8);
  union { uint4 u; bf16x8 v; } cv;
  cv.u = make_uint4(a.x, a.y, b.x, b.y);
  return cv.v;
}

__device__ inline unsigned int fbits(float f) {
  unsigned int u; __builtin_memcpy(&u, &f, 4); return u;
}
__device__ inline float bits2f(unsigned int u) {
  float f; __builtin_memcpy(&f, &u, 4); return f;
}

// pack two f32 -> two bf16 in one dword (round via +0x8000)
__device__ inline unsigned int pack_bf2(float lo, float hi) {
  return __builtin_amdgcn_perm(fbits(hi) + 0x8000u, fbits(lo) + 0x8000u, 0x07060302u);
}
// truncating pack (1 instr) — for P, where the error budget is generous
__device__ inline unsigned int pack_bf2t(float lo, float hi) {
  return __builtin_amdgcn_perm(fbits(hi), fbits(lo), 0x07060302u);
}

// ---------------- GroupNorm partial stats (blocks 0..255) + weight conv (256..511)
__global__ __launch_bounds__(256) void gn_stats_part(const float* __restrict__ x,
                                                     float* __restrict__ parts,
                                                     const float* __restrict__ wq,
                                                     const float* __restrict__ wp,
                                                     unsigned short* __restrict__ wq_b,
                                                     unsigned short* __restrict__ wp_b) {
  if (blockIdx.x >= 256) {
    int base = (blockIdx.x - 256) * 1024 + threadIdx.x * 4;
    #pragma unroll
    for (int k = 0; k < 4; k++) {
      int idx = base + k;
      if (idx < 196608) wq_b[idx] = f2bf(wq[idx]);
      else              wp_b[idx - 196608] = f2bf(wp[idx - 196608]);
    }
    return;
  }
  int i = blockIdx.x;
  const float4* p4 = (const float4*)(x + (size_t)i * 8192);
  int t = threadIdx.x;
  float s = 0.f, ss = 0.f;
  for (int k = t; k < 2048; k += 256) {
    float4 v = p4[k];
    s  += v.x + v.y + v.z + v.w;
    ss += v.x*v.x + v.y*v.y + v.z*v.z + v.w*v.w;
  }
  for (int m = 32; m >= 1; m >>= 1) {
    s  += __shfl_down(s, m, 64);
    ss += __shfl_down(ss, m, 64);
  }
  __shared__ float red[8];
  int w = t >> 6;
  if ((t & 63) == 0) { red[w] = s; red[w + 4] = ss; }
  __syncthreads();
  if (t == 0) {
    parts[i]       = red[0] + red[1] + red[2] + red[3];
    parts[256 + i] = red[4] + red[5] + red[6] + red[7];
  }
}

// ---------------- GroupNorm apply + transpose (finalizes stats from parts)
__global__ __launch_bounds__(256) void gn_apply(const float* __restrict__ x,
                                                const float* __restrict__ parts,
                                                const float* __restrict__ gamma,
                                                const float* __restrict__ beta,
                                                unsigned short* __restrict__ h_t) {
  __shared__ float tile[64][65];
  __shared__ float gmean[8], grstd[8];
  int b = blockIdx.z, c0 = blockIdx.y * 64, s0 = blockIdx.x * 64;
  int t = threadIdx.x;
  if (t < 8) {
    int bg = b * 32 + (c0 >> 3) + t;
    float s  = (parts[4*bg] + parts[4*bg+1]) + (parts[4*bg+2] + parts[4*bg+3]);
    float ss = (parts[256+4*bg] + parts[256+4*bg+1]) + (parts[256+4*bg+2] + parts[256+4*bg+3]);
    float mean = s * (1.0f / 32768.0f);
    float var  = ss * (1.0f / 32768.0f) - mean * mean;
    gmean[t] = mean;
    grstd[t] = rsqrtf(var + 1e-5f);
  }
  const float* xb = x + ((size_t)b * C + c0) * HW + s0;
  #pragma unroll
  for (int k = 0; k < 16; k++) {
    int e = k * 256 + t;
    int i = e >> 6, j = e & 63;
    tile[i][j] = xb[(size_t)i * HW + j];
  }
  __syncthreads();
  unsigned short* hb = h_t + ((size_t)b * HW + s0) * C + c0;
  #pragma unroll
  for (int k = 0; k < 16; k++) {
    int e = k * 256 + t;
    int jr = e >> 6, ir = e & 63;
    int c = c0 + ir, gl = ir >> 3;
    float v = (tile[ir][jr] - gmean[gl]) * grstd[gl] * gamma[c] + beta[c];
    hb[(size_t)jr * C + ir] = f2bf(v);
  }
}

// ---------------- QKV GEMM: packed uint2 epilogue stores for q/k
__global__ __launch_bounds__(256) void qkv_gemm(const unsigned short* __restrict__ wq_b,
                                                const unsigned short* __restrict__ h_t,
                                                const float* __restrict__ b_qkv,
                                                unsigned short* __restrict__ q_t,
                                                unsigned short* __restrict__ k_t,
                                                unsigned short* __restrict__ v_t) {
  int lane = threadIdx.x & 63, w = threadIdx.x >> 6;
  int quad = lane >> 4, l16 = lane & 15;
  int m0 = blockIdx.y * 64 + w * 16;
  int n0 = blockIdx.x * 64;
  int b  = blockIdx.z;
  f32x4 acc[4];
  #pragma unroll
  for (int nb = 0; nb < 4; nb++) acc[nb] = (f32x4){0.f, 0.f, 0.f, 0.f};

  const unsigned short* hb = h_t + (size_t)b * HW * C;
  for (int k0 = 0; k0 < 256; k0 += 32) {
    bf16x8 a = load8(wq_b + (size_t)(m0 + l16) * 256 + k0 + quad * 8);
    #pragma unroll
    for (int nb = 0; nb < 4; nb++) {
      int s = n0 + nb * 16 + l16;
      bf16x8 bb = load8(hb + (size_t)s * C + k0 + quad * 8);
      acc[nb] = __builtin_amdgcn_mfma_f32_16x16x32_bf16(a, bb, acc[nb], 0, 0, 0);
    }
  }

  int seg = m0 >> 8;
  int o0 = m0 + quad * 4;
  #pragma unroll
  for (int nb = 0; nb < 4; nb++) {
    int s = n0 + nb * 16 + l16;
    if (seg == 2) {
      #pragma unroll
      for (int r = 0; r < 4; r++)
        v_t[((size_t)b * C + ((o0 + r) - 512)) * HW + s] = f2bf(acc[nb][r] + b_qkv[o0 + r]);
    } else {
      float sc = seg ? 1.0f : QSCALE;
      float v0 = (acc[nb][0] + b_qkv[o0])     * sc;
      float v1 = (acc[nb][1] + b_qkv[o0 + 1]) * sc;
      float v2 = (acc[nb][2] + b_qkv[o0 + 2]) * sc;
      float v3 = (acc[nb][3] + b_qkv[o0 + 3]) * sc;
      int oc = o0 & 255, h = oc >> 5, d = oc & 31;
      unsigned short* dst = seg ? k_t : q_t;
      uint2 dd;
      dd.x = pack_bf2(v0, v1);
      dd.y = pack_bf2(v2, v3);
      *(uint2*)(dst + (((size_t)b * NH + h) * HW + s) * HD + d) = dd;
    }
  }
}

// softmax on S (one 32-key block) + pack to LDS row
__device__ __forceinline__ void softmax_pack(const f32x16& S, unsigned short* prow,
                                             int hi, f32x2& ps2) {
  float p[16];
  #pragma unroll
  for (int r = 0; r < 16; r++)
    p[r] = __builtin_amdgcn_exp2f(S[r]);
  f32x2 t0 = (f32x2){p[0], p[1]} + (f32x2){p[2], p[3]};
  f32x2 t1 = (f32x2){p[4], p[5]} + (f32x2){p[6], p[7]};
  f32x2 t2 = (f32x2){p[8], p[9]} + (f32x2){p[10], p[11]};
  f32x2 t3 = (f32x2){p[12], p[13]} + (f32x2){p[14], p[15]};
  ps2 += (t0 + t1) + (t2 + t3);
  #pragma unroll
  for (int g = 0; g < 4; g++) {
    uint2 dd;
    dd.x = pack_bf2t(p[4 * g], p[4 * g + 1]);
    dd.y = pack_bf2t(p[4 * g + 2], p[4 * g + 3]);
    *(uint2*)(prow + g * 8 + hi * 4) = dd;
  }
}

// ---------------- Flash v11b: grid (bh=16, qtile=32, split=2), 4 waves/block
__global__ __launch_bounds__(256) void flash_part(const unsigned short* __restrict__ q_t,
                                                  const unsigned short* __restrict__ k_t,
                                                  const unsigned short* __restrict__ v_t,
                                                  unsigned short* __restrict__ po,
                                                  float* __restrict__ pl,
                                                  int jspan) {
  int t = threadIdx.x;
  int lane = t & 63, w = t >> 6;
  int n = lane & 31, hi = lane >> 5, hi8 = hi * 8;
  int bh = blockIdx.x, b = bh >> 3, h = bh & 7;
  int m0 = blockIdx.y * 128 + w * 32;
  int z = blockIdx.z;

  __shared__ __align__(16) unsigned short kt2[2][64 * KST];      // 2 x 4.6 KB [key][d]
  __shared__ __align__(16) unsigned short vt2[2][32 * VST];      // 2 x 4.4 KB [d][key]
  __shared__ __align__(16) unsigned short pbuf[4][2][32 * PST];  // 18.4 KB
  unsigned short* prow0 = &pbuf[w][0][0] + n * PST;
  unsigned short* prow1 = &pbuf[w][1][0] + n * PST;

  const unsigned short* Q  = q_t + (size_t)bh * HW * HD;
  const unsigned short* Kg = k_t + (size_t)bh * HW * HD;
  const unsigned short* Vg = v_t + ((size_t)b * C + h * HD) * HW;

  // B-operand Q fragments: lane holds query n, k = dhalf*16 + hi*8 + j
  bf16x8 qf0 = load8(Q + (size_t)(m0 + n) * HD + hi8);
  bf16x8 qf1 = load8(Q + (size_t)(m0 + n) * HD + 16 + hi8);

  // coalesced staging roles: K tile 64keys x 32d: thread = (key, 16B seg)
  //                          V tile 32d x 64keys: thread = (d, 16B seg)
  int kkey = t >> 2, kseg = (t & 3) * 8;
  int vd   = t >> 3, vseg = (t & 7) * 8;
  const unsigned short* kgp = Kg + (size_t)kkey * HD + kseg;
  const unsigned short* vgp = Vg + (size_t)vd * HW + vseg;

  f32x2 ps2 = (f32x2){0.f, 0.f};
  f32x16 oT = (f32x16){0.f,0.f,0.f,0.f,0.f,0.f,0.f,0.f,0.f,0.f,0.f,0.f,0.f,0.f,0.f,0.f};
  const f32x16 zero16 = (f32x16){0.f,0.f,0.f,0.f,0.f,0.f,0.f,0.f,0.f,0.f,0.f,0.f,0.f,0.f,0.f,0.f};

  int jbase = z * jspan, jend = jbase + jspan;
  uint4 kreg = *(const uint4*)(kgp + (size_t)jbase * HD);
  uint4 vreg = *(const uint4*)(vgp + jbase);

  int phase = 0;
  for (int j0 = jbase; j0 < jend; j0 += 64, phase ^= 1) {
    unsigned short* ktp = &kt2[phase][0];
    unsigned short* vtp = &vt2[phase][0];
    // stage current tile from prefetched regs
    *(uint2*)(ktp + kkey * KST + kseg)     = make_uint2(kreg.x, kreg.y);
    *(uint2*)(ktp + kkey * KST + kseg + 4) = make_uint2(kreg.z, kreg.w);
    *(uint2*)(vtp + vd * VST + vseg)       = make_uint2(vreg.x, vreg.y);
    *(uint2*)(vtp + vd * VST + vseg + 4)   = make_uint2(vreg.z, vreg.w);
    // prefetch next tile (redundant re-read of jbase on last iter; harmless)
    int jn = (j0 + 64 < jend) ? (j0 + 64) : jbase;
    kreg = *(const uint4*)(kgp + (size_t)jn * HD);
    vreg = *(const uint4*)(vgp + jn);
    __syncthreads();   // staged tile visible; prev iter's reads drained (lgkmcnt0)

    // ---- QK^T for both 32-key blocks (A-fragments: +hi8 half-wave offset!)
    const unsigned short* kr0 = ktp + n * KST;
    const unsigned short* kr1 = ktp + (32 + n) * KST;
    bf16x8 ka0 = load8_lds(kr0 + hi8);
    bf16x8 ka1 = load8_lds(kr0 + 16 + hi8);
    bf16x8 kb0 = load8_lds(kr1 + hi8);
    bf16x8 kb1 = load8_lds(kr1 + 16 + hi8);
    f32x16 S0 = __builtin_amdgcn_mfma_f32_32x32x16_bf16(ka1, qf1, zero16, 0, 0, 0);
    S0 = __builtin_amdgcn_mfma_f32_32x32x16_bf16(ka0, qf0, S0, 0, 0, 0);
    f32x16 S1 = __builtin_amdgcn_mfma_f32_32x32x16_bf16(kb1, qf1, zero16, 0, 0, 0);
    S1 = __builtin_amdgcn_mfma_f32_32x32x16_bf16(kb0, qf0, S1, 0, 0, 0);
    // ---- softmax both blocks (64 exp2 between P writes and P reads)
    softmax_pack(S0, prow0, hi, ps2);
    softmax_pack(S1, prow1, hi, ps2);
    // ---- PV: all 4 MFMAs
    const unsigned short* vrow = vtp + n * VST;
    bf16x8 vf0 = load8_lds(vrow + hi8);
    bf16x8 vf1 = load8_lds(vrow + 16 + hi8);
    bf16x8 vf2 = load8_lds(vrow + 32 + hi8);
    bf16x8 vf3 = load8_lds(vrow + 48 + hi8);
    bf16x8 pf0 = load8_lds(prow0 + hi8);
    bf16x8 pf1 = load8_lds(prow0 + 16 + hi8);
    bf16x8 pf2 = load8_lds(prow1 + hi8);
    bf16x8 pf3 = load8_lds(prow1 + 16 + hi8);
    oT = __builtin_amdgcn_mfma_f32_32x32x16_bf16(vf0, pf0, oT, 0, 0, 0);
    oT = __builtin_amdgcn_mfma_f32_32x32x16_bf16(vf1, pf1, oT, 0, 0, 0);
    oT = __builtin_amdgcn_mfma_f32_32x32x16_bf16(vf2, pf2, oT, 0, 0, 0);
    oT = __builtin_amdgcn_mfma_f32_32x32x16_bf16(vf3, pf3, oT, 0, 0, 0);
  }

  float psum = ps2.x + ps2.y;
  psum += __shfl_xor(psum, 32, 64);

  // O^T partials (bf16): col=query n, row d = (reg&3)+8*(reg>>2)+4*hi
  unsigned short* pr = po + (((size_t)z * 16 + bh) * HW + (m0 + n)) * 32;
  #pragma unroll
  for (int g = 0; g < 4; g++) {
    uint2 dd;
    dd.x = pack_bf2(oT[4 * g], oT[4 * g + 1]);
    dd.y = pack_bf2(oT[4 * g + 2], oT[4 * g + 3]);
    *(uint2*)(pr + g * 8 + hi * 4) = dd;
  }
  if (lane < 32)
    pl[((size_t)z * 16 + bh) * HW + m0 + n] = psum;
}

// ---------------- merge 2 partials -> ao_t[b][s][c] bf16
__global__ __launch_bounds__(256) void merge_parts(const unsigned short* __restrict__ po,
                                                   const float* __restrict__ pl,
                                                   unsigned short* __restrict__ ao_t) {
  int g = blockIdx.x * 256 + threadIdx.x;   // [0, 16*4096*4)
  int q4 = g & 3, s = (g >> 2) & 4095, bh = g >> 14;
  const uint4* p4 = (const uint4*)po;
  size_t idx = ((size_t)bh * HW + s) * 4 + q4;
  const size_t zstride = (size_t)16 * HW * 4;
  float acc[8] = {0,0,0,0,0,0,0,0};
  float l = 0.f;
  #pragma unroll
  for (int z = 0; z < 2; z++) {
    uint4 v = p4[z * zstride + idx];
    acc[0] += bits2f(v.x << 16);  acc[1] += bits2f(v.x & 0xffff0000u);
    acc[2] += bits2f(v.y << 16);  acc[3] += bits2f(v.y & 0xffff0000u);
    acc[4] += bits2f(v.z << 16);  acc[5] += bits2f(v.z & 0xffff0000u);
    acc[6] += bits2f(v.w << 16);  acc[7] += bits2f(v.w & 0xffff0000u);
    l += pl[((size_t)z * 16 + bh) * HW + s];
  }
  float inv = 1.0f / l;
  int b = bh >> 3, h = bh & 7;
  uint4 o;
  o.x = pack_bf2(acc[0] * inv, acc[1] * inv);
  o.y = pack_bf2(acc[2] * inv, acc[3] * inv);
  o.z = pack_bf2(acc[4] * inv, acc[5] * inv);
  o.w = pack_bf2(acc[6] * inv, acc[7] * inv);
  *(uint4*)(ao_t + ((size_t)b * HW + s) * C + h * HD + q4 * 8) = o;
}

// ---------------- Proj GEMM + bias + residual
__global__ __launch_bounds__(256) void proj_gemm(const unsigned short* __restrict__ wp_b,
                                                 const unsigned short* __restrict__ ao_t,
                                                 const float* __restrict__ b_proj,
                                                 const float* __restrict__ x,
                                                 float* __restrict__ out) {
  int lane = threadIdx.x & 63, w = threadIdx.x >> 6;
  int quad = lane >> 4, l16 = lane & 15;
  int m0 = blockIdx.y * 64 + w * 16;
  int n0 = blockIdx.x * 64;
  int b  = blockIdx.z;
  f32x4 acc[4];
  #pragma unroll
  for (int nb = 0; nb < 4; nb++) acc[nb] = (f32x4){0.f, 0.f, 0.f, 0.f};

  const unsigned short* ab = ao_t + (size_t)b * HW * C;
  for (int k0 = 0; k0 < 256; k0 += 32) {
    bf16x8 a = load8(wp_b + (size_t)(m0 + l16) * 256 + k0 + quad * 8);
    #pragma unroll
    for (int nb = 0; nb < 4; nb++) {
      int s = n0 + nb * 16 + l16;
      bf16x8 bb = load8(ab + (size_t)s * C + k0 + quad * 8);
      acc[nb] = __builtin_amdgcn_mfma_f32_16x16x32_bf16(a, bb, acc[nb], 0, 0, 0);
    }
  }
  #pragma unroll
  for (int nb = 0; nb < 4; nb++) {
    int s = n0 + nb * 16 + l16;
    #pragma unroll
    for (int r = 0; r < 4; r++) {
      int o = m0 + quad * 4 + r;
      size_t idx = ((size_t)b * C + o) * HW + s;
      out[idx] = acc[nb][r] + b_proj[o] + x[idx];
    }
  }
}

extern "C" void kernel_launch(void* const* d_in, const int* in_sizes, int n_in,
                              void* d_out, int out_size, void* d_ws, size_t ws_size,
                              hipStream_t stream) {
  const float* x      = (const float*)d_in[0];
  const float* w_qkv  = (const float*)d_in[1];
  const float* b_qkv  = (const float*)d_in[2];
  const float* w_proj = (const float*)d_in[3];
  const float* b_proj = (const float*)d_in[4];
  const float* gamma  = (const float*)d_in[5];
  const float* beta   = (const float*)d_in[6];
  float* out = (float*)d_out;

  char* ws = (char*)d_ws;
  float*          parts = (float*)ws;                          // 2 KB
  unsigned short* wq_b  = (unsigned short*)(ws + 4096);        // 384 KB
  unsigned short* wp_b  = (unsigned short*)(ws + 397312);      // 128 KB
  unsigned short* h_t   = (unsigned short*)(ws + 528384);      // 4 MB [b][s][c]; reused as ao_t
  unsigned short* q_t   = (unsigned short*)(ws + 4722688);     // 4 MB [bh][s][d]
  unsigned short* k_t   = (unsigned short*)(ws + 8916992);     // 4 MB [bh][s][d]
  unsigned short* v_t   = (unsigned short*)(ws + 13111296);    // 4 MB [b][c][s]
  unsigned short* po    = (unsigned short*)(ws + 17305600);    // 8 MB (2 splits, bf16)
  float*          pl    = (float*)(ws + 34082816);             // 512 KB
  unsigned short* ao_t  = h_t;  // h_t dead after qkv_gemm

  gn_stats_part<<<512, 256, 0, stream>>>(x, parts, w_qkv, w_proj, wq_b, wp_b);
  gn_apply<<<dim3(64, 4, 2), 256, 0, stream>>>(x, parts, gamma, beta, h_t);
  qkv_gemm<<<dim3(64, 12, 2), 256, 0, stream>>>(wq_b, h_t, b_qkv, q_t, k_t, v_t);
  flash_part<<<dim3(16, 32, 2), 256, 0, stream>>>(q_t, k_t, v_t, po, pl, HW / 2);
  merge_parts<<<1024, 256, 0, stream>>>(po, pl, ao_t);
  proj_gemm<<<dim3(64, 4, 2), 256, 0, stream>>>(wp_b, ao_t, b_proj, x, out);
}

// Round 13
// 161.354 us; speedup vs baseline: 1.3778x; 1.1373x over previous
//
#include <hip/hip_runtime.h>
#include <hip/hip_bf16.h>

// ScoreAttention on MI355X (gfx950).
// Pipeline: gn_stats_part+convert_w(tiled) -> gn_apply(tiled h) -> qkv_gemm(staged)
//           -> flash_part(x2 K-split) -> merge_parts(tiled ao) -> proj_gemm(staged)
// R13: W / h_t / ao_t stored in [mblk][kblk][64][32] tiles so the GEMM K-loops
// stage operands with perfectly-linear uint4 reads (1 per thread per tile) into
// double-buffered LDS -- same coalescing fix that took flash 105->71us (v10).
// flash v11b unchanged.

typedef __attribute__((ext_vector_type(8))) __bf16 bf16x8;
typedef __attribute__((ext_vector_type(4))) float f32x4;
typedef __attribute__((ext_vector_type(2))) float f32x2;
typedef __attribute__((ext_vector_type(16))) float f32x16;

#define HW 4096
#define C 256
#define NH 8
#define HD 32
#define QSCALE 0.25505654f  /* log2(e)/sqrt(32) */
#define KST 36   /* flash K tile row stride */
#define VST 68   /* flash V tile row stride */
#define PST 36   /* flash P row stride */
#define TST 36   /* GEMM LDS tile row stride (32 + 4 pad shorts) */

__device__ inline unsigned short f2bf(float f) {
  union { float f; unsigned int u; } v; v.f = f;
  unsigned int u = v.u;
  return (unsigned short)((u + 0x7fffu + ((u >> 16) & 1u)) >> 16);
}

__device__ inline bf16x8 load8(const unsigned short* p) {
  bf16x8 v;
  __builtin_memcpy(&v, __builtin_assume_aligned(p, 16), 16);
  return v;
}

// 8B-aligned LDS read of 8 bf16 as two b64s
__device__ inline bf16x8 load8_lds(const unsigned short* p) {
  uint2 a = *(const uint2*)__builtin_assume_aligned(p, 8);
  uint2 b = *(const uint2*)__builtin_assume_aligned(p + 4, 8);
  union { uint4 u; bf16x8 v; } cv;
  cv.u = make_uint4(a.x, a.y, b.x, b.y);
  return cv.v;
}

__device__ inline unsigned int fbits(float f) {
  unsigned int u; __builtin_memcpy(&u, &f, 4); return u;
}
__device__ inline float bits2f(unsigned int u) {
  float f; __builtin_memcpy(&f, &u, 4); return f;
}

// pack two f32 -> two bf16 in one dword (round via +0x8000)
__device__ inline unsigned int pack_bf2(float lo, float hi) {
  return __builtin_amdgcn_perm(fbits(hi) + 0x8000u, fbits(lo) + 0x8000u, 0x07060302u);
}
// truncating pack (1 instr) — for P, where the error budget is generous
__device__ inline unsigned int pack_bf2t(float lo, float hi) {
  return __builtin_amdgcn_perm(fbits(hi), fbits(lo), 0x07060302u);
}

// tiled weight/activation offset: [mblk][kblk][64][32]
__device__ inline size_t toff(int row, int col) {
  return ((size_t)(row >> 6) * 8 + (col >> 5)) * 2048 + (row & 63) * 32 + (col & 31);
}

// ---------------- GroupNorm partial stats (blocks 0..255) + weight conv (256..511)
__global__ __launch_bounds__(256) void gn_stats_part(const float* __restrict__ x,
                                                     float* __restrict__ parts,
                                                     const float* __restrict__ wq,
                                                     const float* __restrict__ wp,
                                                     unsigned short* __restrict__ wq_t,
                                                     unsigned short* __restrict__ wp_t) {
  if (blockIdx.x >= 256) {
    int base = (blockIdx.x - 256) * 1024 + threadIdx.x * 4;
    #pragma unroll
    for (int k = 0; k < 4; k++) {
      int idx = base + k;
      if (idx < 196608) {
        int o = idx >> 8, c = idx & 255;
        wq_t[toff(o, c)] = f2bf(wq[idx]);
      } else {
        int i2 = idx - 196608;
        int o = i2 >> 8, c = i2 & 255;
        wp_t[toff(o, c)] = f2bf(wp[i2]);
      }
    }
    return;
  }
  int i = blockIdx.x;
  const float4* p4 = (const float4*)(x + (size_t)i * 8192);
  int t = threadIdx.x;
  float s = 0.f, ss = 0.f;
  for (int k = t; k < 2048; k += 256) {
    float4 v = p4[k];
    s  += v.x + v.y + v.z + v.w;
    ss += v.x*v.x + v.y*v.y + v.z*v.z + v.w*v.w;
  }
  for (int m = 32; m >= 1; m >>= 1) {
    s  += __shfl_down(s, m, 64);
    ss += __shfl_down(ss, m, 64);
  }
  __shared__ float red[8];
  int w = t >> 6;
  if ((t & 63) == 0) { red[w] = s; red[w + 4] = ss; }
  __syncthreads();
  if (t == 0) {
    parts[i]       = red[0] + red[1] + red[2] + red[3];
    parts[256 + i] = red[4] + red[5] + red[6] + red[7];
  }
}

// ---------------- GroupNorm apply + transpose -> tiled h layout
__global__ __launch_bounds__(256) void gn_apply(const float* __restrict__ x,
                                                const float* __restrict__ parts,
                                                const float* __restrict__ gamma,
                                                const float* __restrict__ beta,
                                                unsigned short* __restrict__ h_t) {
  __shared__ float tile[64][65];
  __shared__ float gmean[8], grstd[8];
  int b = blockIdx.z, c0 = blockIdx.y * 64, s0 = blockIdx.x * 64;
  int t = threadIdx.x;
  if (t < 8) {
    int bg = b * 32 + (c0 >> 3) + t;
    float s  = (parts[4*bg] + parts[4*bg+1]) + (parts[4*bg+2] + parts[4*bg+3]);
    float ss = (parts[256+4*bg] + parts[256+4*bg+1]) + (parts[256+4*bg+2] + parts[256+4*bg+3]);
    float mean = s * (1.0f / 32768.0f);
    float var  = ss * (1.0f / 32768.0f) - mean * mean;
    gmean[t] = mean;
    grstd[t] = rsqrtf(var + 1e-5f);
  }
  const float* xb = x + ((size_t)b * C + c0) * HW + s0;
  #pragma unroll
  for (int k = 0; k < 16; k++) {
    int e = k * 256 + t;
    int i = e >> 6, j = e & 63;
    tile[i][j] = xb[(size_t)i * HW + j];
  }
  __syncthreads();
  // tiled store: base tile (sblk = s0>>6, kblk = c0>>5)
  unsigned short* hb = h_t + (size_t)b * HW * C +
                       ((size_t)(s0 >> 6) * 8 + (c0 >> 5)) * 2048;
  #pragma unroll
  for (int k = 0; k < 16; k++) {
    int e = k * 256 + t;
    int jr = e >> 6, ir = e & 63;
    int c = c0 + ir, gl = ir >> 3;
    float v = (tile[ir][jr] - gmean[gl]) * grstd[gl] * gamma[c] + beta[c];
    hb[(ir >> 5) * 2048 + jr * 32 + (ir & 31)] = f2bf(v);
  }
}

// ---------------- QKV GEMM v2: staged tiled operands, double-buffered LDS
__global__ __launch_bounds__(256) void qkv_gemm(const unsigned short* __restrict__ wq_t,
                                                const unsigned short* __restrict__ h_t,
                                                const float* __restrict__ b_qkv,
                                                unsigned short* __restrict__ q_t,
                                                unsigned short* __restrict__ k_t,
                                                unsigned short* __restrict__ v_t) {
  int t = threadIdx.x;
  int lane = t & 63, w = t >> 6;
  int quad = lane >> 4, l16 = lane & 15;
  int m0 = blockIdx.y * 64 + w * 16;
  int n0 = blockIdx.x * 64;
  int b  = blockIdx.z;

  __shared__ __align__(16) unsigned short at2[2][64 * TST];
  __shared__ __align__(16) unsigned short bt2[2][64 * TST];

  const uint4* Ag = (const uint4*)(wq_t + (size_t)blockIdx.y * 8 * 2048);
  const uint4* Bg = (const uint4*)(h_t + (size_t)b * HW * C + (size_t)blockIdx.x * 8 * 2048);
  int lrow = t >> 2, lcol = (t & 3) * 8;

  f32x4 acc[4];
  #pragma unroll
  for (int nb = 0; nb < 4; nb++) acc[nb] = (f32x4){0.f, 0.f, 0.f, 0.f};

  uint4 areg = Ag[t];
  uint4 breg = Bg[t];
  int phase = 0;
  for (int k = 0; k < 8; k++, phase ^= 1) {
    unsigned short* ap = &at2[phase][0];
    unsigned short* bp = &bt2[phase][0];
    *(uint2*)(ap + lrow * TST + lcol)     = make_uint2(areg.x, areg.y);
    *(uint2*)(ap + lrow * TST + lcol + 4) = make_uint2(areg.z, areg.w);
    *(uint2*)(bp + lrow * TST + lcol)     = make_uint2(breg.x, breg.y);
    *(uint2*)(bp + lrow * TST + lcol + 4) = make_uint2(breg.z, breg.w);
    int kn = (k < 7) ? k + 1 : 7;
    areg = Ag[kn * 256 + t];
    breg = Bg[kn * 256 + t];
    __syncthreads();
    bf16x8 a = load8_lds(ap + (w * 16 + l16) * TST + quad * 8);
    #pragma unroll
    for (int nb = 0; nb < 4; nb++) {
      bf16x8 bb = load8_lds(bp + (nb * 16 + l16) * TST + quad * 8);
      acc[nb] = __builtin_amdgcn_mfma_f32_16x16x32_bf16(a, bb, acc[nb], 0, 0, 0);
    }
  }

  int seg = m0 >> 8;
  int o0 = m0 + quad * 4;
  #pragma unroll
  for (int nb = 0; nb < 4; nb++) {
    int s = n0 + nb * 16 + l16;
    if (seg == 2) {
      #pragma unroll
      for (int r = 0; r < 4; r++)
        v_t[((size_t)b * C + ((o0 + r) - 512)) * HW + s] = f2bf(acc[nb][r] + b_qkv[o0 + r]);
    } else {
      float sc = seg ? 1.0f : QSCALE;
      float v0 = (acc[nb][0] + b_qkv[o0])     * sc;
      float v1 = (acc[nb][1] + b_qkv[o0 + 1]) * sc;
      float v2 = (acc[nb][2] + b_qkv[o0 + 2]) * sc;
      float v3 = (acc[nb][3] + b_qkv[o0 + 3]) * sc;
      int oc = o0 & 255, h = oc >> 5, d = oc & 31;
      unsigned short* dst = seg ? k_t : q_t;
      uint2 dd;
      dd.x = pack_bf2(v0, v1);
      dd.y = pack_bf2(v2, v3);
      *(uint2*)(dst + (((size_t)b * NH + h) * HW + s) * HD + d) = dd;
    }
  }
}

// softmax on S (one 32-key block) + pack to LDS row
__device__ __forceinline__ void softmax_pack(const f32x16& S, unsigned short* prow,
                                             int hi, f32x2& ps2) {
  float p[16];
  #pragma unroll
  for (int r = 0; r < 16; r++)
    p[r] = __builtin_amdgcn_exp2f(S[r]);
  f32x2 t0 = (f32x2){p[0], p[1]} + (f32x2){p[2], p[3]};
  f32x2 t1 = (f32x2){p[4], p[5]} + (f32x2){p[6], p[7]};
  f32x2 t2 = (f32x2){p[8], p[9]} + (f32x2){p[10], p[11]};
  f32x2 t3 = (f32x2){p[12], p[13]} + (f32x2){p[14], p[15]};
  ps2 += (t0 + t1) + (t2 + t3);
  #pragma unroll
  for (int g = 0; g < 4; g++) {
    uint2 dd;
    dd.x = pack_bf2t(p[4 * g], p[4 * g + 1]);
    dd.y = pack_bf2t(p[4 * g + 2], p[4 * g + 3]);
    *(uint2*)(prow + g * 8 + hi * 4) = dd;
  }
}

// ---------------- Flash v11b (unchanged): grid (bh=16, qtile=32, split=2)
__global__ __launch_bounds__(256) void flash_part(const unsigned short* __restrict__ q_t,
                                                  const unsigned short* __restrict__ k_t,
                                                  const unsigned short* __restrict__ v_t,
                                                  unsigned short* __restrict__ po,
                                                  float* __restrict__ pl,
                                                  int jspan) {
  int t = threadIdx.x;
  int lane = t & 63, w = t >> 6;
  int n = lane & 31, hi = lane >> 5, hi8 = hi * 8;
  int bh = blockIdx.x, b = bh >> 3, h = bh & 7;
  int m0 = blockIdx.y * 128 + w * 32;
  int z = blockIdx.z;

  __shared__ __align__(16) unsigned short kt2[2][64 * KST];
  __shared__ __align__(16) unsigned short vt2[2][32 * VST];
  __shared__ __align__(16) unsigned short pbuf[4][2][32 * PST];
  unsigned short* prow0 = &pbuf[w][0][0] + n * PST;
  unsigned short* prow1 = &pbuf[w][1][0] + n * PST;

  const unsigned short* Q  = q_t + (size_t)bh * HW * HD;
  const unsigned short* Kg = k_t + (size_t)bh * HW * HD;
  const unsigned short* Vg = v_t + ((size_t)b * C + h * HD) * HW;

  bf16x8 qf0 = load8(Q + (size_t)(m0 + n) * HD + hi8);
  bf16x8 qf1 = load8(Q + (size_t)(m0 + n) * HD + 16 + hi8);

  int kkey = t >> 2, kseg = (t & 3) * 8;
  int vd   = t >> 3, vseg = (t & 7) * 8;
  const unsigned short* kgp = Kg + (size_t)kkey * HD + kseg;
  const unsigned short* vgp = Vg + (size_t)vd * HW + vseg;

  f32x2 ps2 = (f32x2){0.f, 0.f};
  f32x16 oT = (f32x16){0.f,0.f,0.f,0.f,0.f,0.f,0.f,0.f,0.f,0.f,0.f,0.f,0.f,0.f,0.f,0.f};
  const f32x16 zero16 = (f32x16){0.f,0.f,0.f,0.f,0.f,0.f,0.f,0.f,0.f,0.f,0.f,0.f,0.f,0.f,0.f,0.f};

  int jbase = z * jspan, jend = jbase + jspan;
  uint4 kreg = *(const uint4*)(kgp + (size_t)jbase * HD);
  uint4 vreg = *(const uint4*)(vgp + jbase);

  int phase = 0;
  for (int j0 = jbase; j0 < jend; j0 += 64, phase ^= 1) {
    unsigned short* ktp = &kt2[phase][0];
    unsigned short* vtp = &vt2[phase][0];
    *(uint2*)(ktp + kkey * KST + kseg)     = make_uint2(kreg.x, kreg.y);
    *(uint2*)(ktp + kkey * KST + kseg + 4) = make_uint2(kreg.z, kreg.w);
    *(uint2*)(vtp + vd * VST + vseg)       = make_uint2(vreg.x, vreg.y);
    *(uint2*)(vtp + vd * VST + vseg + 4)   = make_uint2(vreg.z, vreg.w);
    int jn = (j0 + 64 < jend) ? (j0 + 64) : jbase;
    kreg = *(const uint4*)(kgp + (size_t)jn * HD);
    vreg = *(const uint4*)(vgp + jn);
    __syncthreads();

    const unsigned short* kr0 = ktp + n * KST;
    const unsigned short* kr1 = ktp + (32 + n) * KST;
    bf16x8 ka0 = load8_lds(kr0 + hi8);
    bf16x8 ka1 = load8_lds(kr0 + 16 + hi8);
    bf16x8 kb0 = load8_lds(kr1 + hi8);
    bf16x8 kb1 = load8_lds(kr1 + 16 + hi8);
    f32x16 S0 = __builtin_amdgcn_mfma_f32_32x32x16_bf16(ka1, qf1, zero16, 0, 0, 0);
    S0 = __builtin_amdgcn_mfma_f32_32x32x16_bf16(ka0, qf0, S0, 0, 0, 0);
    f32x16 S1 = __builtin_amdgcn_mfma_f32_32x32x16_bf16(kb1, qf1, zero16, 0, 0, 0);
    S1 = __builtin_amdgcn_mfma_f32_32x32x16_bf16(kb0, qf0, S1, 0, 0, 0);
    softmax_pack(S0, prow0, hi, ps2);
    softmax_pack(S1, prow1, hi, ps2);
    const unsigned short* vrow = vtp + n * VST;
    bf16x8 vf0 = load8_lds(vrow + hi8);
    bf16x8 vf1 = load8_lds(vrow + 16 + hi8);
    bf16x8 vf2 = load8_lds(vrow + 32 + hi8);
    bf16x8 vf3 = load8_lds(vrow + 48 + hi8);
    bf16x8 pf0 = load8_lds(prow0 + hi8);
    bf16x8 pf1 = load8_lds(prow0 + 16 + hi8);
    bf16x8 pf2 = load8_lds(prow1 + hi8);
    bf16x8 pf3 = load8_lds(prow1 + 16 + hi8);
    oT = __builtin_amdgcn_mfma_f32_32x32x16_bf16(vf0, pf0, oT, 0, 0, 0);
    oT = __builtin_amdgcn_mfma_f32_32x32x16_bf16(vf1, pf1, oT, 0, 0, 0);
    oT = __builtin_amdgcn_mfma_f32_32x32x16_bf16(vf2, pf2, oT, 0, 0, 0);
    oT = __builtin_amdgcn_mfma_f32_32x32x16_bf16(vf3, pf3, oT, 0, 0, 0);
  }

  float psum = ps2.x + ps2.y;
  psum += __shfl_xor(psum, 32, 64);

  unsigned short* pr = po + (((size_t)z * 16 + bh) * HW + (m0 + n)) * 32;
  #pragma unroll
  for (int g = 0; g < 4; g++) {
    uint2 dd;
    dd.x = pack_bf2(oT[4 * g], oT[4 * g + 1]);
    dd.y = pack_bf2(oT[4 * g + 2], oT[4 * g + 3]);
    *(uint2*)(pr + g * 8 + hi * 4) = dd;
  }
  if (lane < 32)
    pl[((size_t)z * 16 + bh) * HW + m0 + n] = psum;
}

// ---------------- merge 2 partials -> ao_t (tiled layout) bf16
__global__ __launch_bounds__(256) void merge_parts(const unsigned short* __restrict__ po,
                                                   const float* __restrict__ pl,
                                                   unsigned short* __restrict__ ao_t) {
  int g = blockIdx.x * 256 + threadIdx.x;   // [0, 16*4096*4)
  int q4 = g & 3, s = (g >> 2) & 4095, bh = g >> 14;
  const uint4* p4 = (const uint4*)po;
  size_t idx = ((size_t)bh * HW + s) * 4 + q4;
  const size_t zstride = (size_t)16 * HW * 4;
  float acc[8] = {0,0,0,0,0,0,0,0};
  float l = 0.f;
  #pragma unroll
  for (int z = 0; z < 2; z++) {
    uint4 v = p4[z * zstride + idx];
    acc[0] += bits2f(v.x << 16);  acc[1] += bits2f(v.x & 0xffff0000u);
    acc[2] += bits2f(v.y << 16);  acc[3] += bits2f(v.y & 0xffff0000u);
    acc[4] += bits2f(v.z << 16);  acc[5] += bits2f(v.z & 0xffff0000u);
    acc[6] += bits2f(v.w << 16);  acc[7] += bits2f(v.w & 0xffff0000u);
    l += pl[((size_t)z * 16 + bh) * HW + s];
  }
  float inv = 1.0f / l;
  int b = bh >> 3, h = bh & 7;
  uint4 o;
  o.x = pack_bf2(acc[0] * inv, acc[1] * inv);
  o.y = pack_bf2(acc[2] * inv, acc[3] * inv);
  o.z = pack_bf2(acc[4] * inv, acc[5] * inv);
  o.w = pack_bf2(acc[6] * inv, acc[7] * inv);
  // tiled: c = h*32 + q4*8 -> kblk = h, in-row col = q4*8
  *(uint4*)(ao_t + (size_t)b * HW * C +
            ((size_t)(s >> 6) * 8 + h) * 2048 + (s & 63) * 32 + q4 * 8) = o;
}

// ---------------- Proj GEMM v2: staged tiled operands + bias + residual
__global__ __launch_bounds__(256) void proj_gemm(const unsigned short* __restrict__ wp_t,
                                                 const unsigned short* __restrict__ ao_t,
                                                 const float* __restrict__ b_proj,
                                                 const float* __restrict__ x,
                                                 float* __restrict__ out) {
  int t = threadIdx.x;
  int lane = t & 63, w = t >> 6;
  int quad = lane >> 4, l16 = lane & 15;
  int m0 = blockIdx.y * 64 + w * 16;
  int n0 = blockIdx.x * 64;
  int b  = blockIdx.z;

  __shared__ __align__(16) unsigned short at2[2][64 * TST];
  __shared__ __align__(16) unsigned short bt2[2][64 * TST];

  const uint4* Ag = (const uint4*)(wp_t + (size_t)blockIdx.y * 8 * 2048);
  const uint4* Bg = (const uint4*)(ao_t + (size_t)b * HW * C + (size_t)blockIdx.x * 8 * 2048);
  int lrow = t >> 2, lcol = (t & 3) * 8;

  f32x4 acc[4];
  #pragma unroll
  for (int nb = 0; nb < 4; nb++) acc[nb] = (f32x4){0.f, 0.f, 0.f, 0.f};

  uint4 areg = Ag[t];
  uint4 breg = Bg[t];
  int phase = 0;
  for (int k = 0; k < 8; k++, phase ^= 1) {
    unsigned short* ap = &at2[phase][0];
    unsigned short* bp = &bt2[phase][0];
    *(uint2*)(ap + lrow * TST + lcol)     = make_uint2(areg.x, areg.y);
    *(uint2*)(ap + lrow * TST + lcol + 4) = make_uint2(areg.z, areg.w);
    *(uint2*)(bp + lrow * TST + lcol)     = make_uint2(breg.x, breg.y);
    *(uint2*)(bp + lrow * TST + lcol + 4) = make_uint2(breg.z, breg.w);
    int kn = (k < 7) ? k + 1 : 7;
    areg = Ag[kn * 256 + t];
    breg = Bg[kn * 256 + t];
    __syncthreads();
    bf16x8 a = load8_lds(ap + (w * 16 + l16) * TST + quad * 8);
    #pragma unroll
    for (int nb = 0; nb < 4; nb++) {
      bf16x8 bb = load8_lds(bp + (nb * 16 + l16) * TST + quad * 8);
      acc[nb] = __builtin_amdgcn_mfma_f32_16x16x32_bf16(a, bb, acc[nb], 0, 0, 0);
    }
  }
  #pragma unroll
  for (int nb = 0; nb < 4; nb++) {
    int s = n0 + nb * 16 + l16;
    #pragma unroll
    for (int r = 0; r < 4; r++) {
      int o = m0 + quad * 4 + r;
      size_t idx = ((size_t)b * C + o) * HW + s;
      out[idx] = acc[nb][r] + b_proj[o] + x[idx];
    }
  }
}

extern "C" void kernel_launch(void* const* d_in, const int* in_sizes, int n_in,
                              void* d_out, int out_size, void* d_ws, size_t ws_size,
                              hipStream_t stream) {
  const float* x      = (const float*)d_in[0];
  const float* w_qkv  = (const float*)d_in[1];
  const float* b_qkv  = (const float*)d_in[2];
  const float* w_proj = (const float*)d_in[3];
  const float* b_proj = (const float*)d_in[4];
  const float* gamma  = (const float*)d_in[5];
  const float* beta   = (const float*)d_in[6];
  float* out = (float*)d_out;

  char* ws = (char*)d_ws;
  float*          parts = (float*)ws;                          // 2 KB
  unsigned short* wq_t  = (unsigned short*)(ws + 4096);        // 384 KB (tiled)
  unsigned short* wp_t  = (unsigned short*)(ws + 397312);      // 128 KB (tiled)
  unsigned short* h_t   = (unsigned short*)(ws + 528384);      // 4 MB tiled; reused as ao_t
  unsigned short* q_t   = (unsigned short*)(ws + 4722688);     // 4 MB [bh][s][d]
  unsigned short* k_t   = (unsigned short*)(ws + 8916992);     // 4 MB [bh][s][d]
  unsigned short* v_t   = (unsigned short*)(ws + 13111296);    // 4 MB [b][c][s]
  unsigned short* po    = (unsigned short*)(ws + 17305600);    // 8 MB (2 splits, bf16)
  float*          pl    = (float*)(ws + 34082816);             // 512 KB
  unsigned short* ao_t  = h_t;  // h_t dead after qkv_gemm

  gn_stats_part<<<512, 256, 0, stream>>>(x, parts, w_qkv, w_proj, wq_t, wp_t);
  gn_apply<<<dim3(64, 4, 2), 256, 0, stream>>>(x, parts, gamma, beta, h_t);
  qkv_gemm<<<dim3(64, 12, 2), 256, 0, stream>>>(wq_t, h_t, b_qkv, q_t, k_t, v_t);
  flash_part<<<dim3(16, 32, 2), 256, 0, stream>>>(q_t, k_t, v_t, po, pl, HW / 2);
  merge_parts<<<1024, 256, 0, stream>>>(po, pl, ao_t);
  proj_gemm<<<dim3(64, 4, 2), 256, 0, stream>>>(wp_t, ao_t, b_proj, x, out);
}